// Round 12
// baseline (1030.505 us; speedup 1.0000x reference)
//
#include <hip/hip_runtime.h>
#include <cstddef>

#define T_     8000
#define L_     803
#define C_     256
#define D_     512
#define NB_    32
#define FK_    20
#define NBATCH 4
#define EPS_   1e-5f

#define NBLK   52            // 13 l-tiles x 4 batch; one block owns full C/D of a strip
#define NTHR   512           // 8 waves
#define NTH_G  (NBLK * NTHR)
#define SG     1040          // LDS k-group stride bytes: 64 cols * 16B + 16B pad

typedef __attribute__((ext_vector_type(8))) short bf16x8;
typedef __attribute__((ext_vector_type(4))) short shortx4;
typedef __attribute__((ext_vector_type(4))) float f32x4;

__device__ __forceinline__ short f2bf(float x) {
  unsigned u = __float_as_uint(x);
  u += 0x7FFF + ((u >> 16) & 1);   // RNE
  return (short)(u >> 16);
}
__device__ __forceinline__ float bf2f(short u) {
  return __uint_as_float(((unsigned)(unsigned short)u) << 16);
}

struct __align__(64) Bar { unsigned cnt; unsigned phase; unsigned pad[14]; };

__device__ __forceinline__ void bar_heavy(Bar* b, unsigned nblk, int tid) {
  __syncthreads();
  if (tid == 0) {
    __threadfence();
    unsigned ph = __hip_atomic_load(&b->phase, __ATOMIC_RELAXED, __HIP_MEMORY_SCOPE_AGENT);
    unsigned prev = __hip_atomic_fetch_add(&b->cnt, 1u, __ATOMIC_RELAXED, __HIP_MEMORY_SCOPE_AGENT);
    if (prev == nblk - 1) {
      __hip_atomic_store(&b->cnt, 0u, __ATOMIC_RELAXED, __HIP_MEMORY_SCOPE_AGENT);
      __hip_atomic_store(&b->phase, ph + 1u, __ATOMIC_RELEASE, __HIP_MEMORY_SCOPE_AGENT);
    } else {
      while (__hip_atomic_load(&b->phase, __ATOMIC_RELAXED, __HIP_MEMORY_SCOPE_AGENT) == ph)
        __builtin_amdgcn_s_sleep(2);
    }
    __threadfence();
  }
  __syncthreads();
}

struct KParams {
  const float *x, *w_enc, *w1, *wd, *w2, *w_dec;
  const float *g1, *bb1, *m1, *v1;
  const float *g2, *bb2, *m2, *v2;
  const float *g3, *bb3, *m3, *v3;
  float *out;
  float *s1, *o1, *s2, *o2, *s3, *o3;
  float *yb;                  // y [n][l][c] f32
  short *w1b, *w2b;           // bf16 weights
  unsigned short *zg;         // z publish: [layer][blk][64][512] bf16 (rotated)
  unsigned *ct;               // per-block monotone layer counter [52]
  Bar *gbar;
};

// ---------- full-grid prep: BN fold + weight bf16 conversion ----------
__global__ __launch_bounds__(256) void prep_kernel(KParams p) {
  const int gtid = blockIdx.x * 256 + threadIdx.x;
  const int stride = gridDim.x * 256;
  for (int i = gtid; i < NB_ * C_; i += stride) {
    float s = p.g1[i] * rsqrtf(p.v1[i] + EPS_);
    p.s1[i] = s; p.o1[i] = p.bb1[i] - p.m1[i] * s;
  }
  for (int i = gtid; i < NB_ * D_; i += stride) {
    float s2 = p.g2[i] * rsqrtf(p.v2[i] + EPS_);
    p.s2[i] = s2; p.o2[i] = p.bb2[i] - p.m2[i] * s2;
    float s3 = p.g3[i] * rsqrtf(p.v3[i] + EPS_);
    p.s3[i] = s3; p.o3[i] = p.bb3[i] - p.m3[i] * s3;
  }
  for (int i = gtid; i < NB_ * D_ * C_ / 4; i += stride) {
    float4 a = ((const float4*)p.w1)[i];
    float4 b = ((const float4*)p.w2)[i];
    shortx4 sa, sb;
    sa[0] = f2bf(a.x); sa[1] = f2bf(a.y); sa[2] = f2bf(a.z); sa[3] = f2bf(a.w);
    sb[0] = f2bf(b.x); sb[1] = f2bf(b.y); sb[2] = f2bf(b.z); sb[3] = f2bf(b.w);
    *(shortx4*)&p.w1b[4 * i] = sa;
    *(shortx4*)&p.w2b[4 * i] = sb;
  }
}

__global__ __launch_bounds__(NTHR, 2) void tasnet_fused(KParams p) {
  const int tid = threadIdx.x;
  const int bid = blockIdx.x;
  const int gtid = bid * NTHR + tid;

  const int xt = bid % 13, n = bid / 13;
  const int l0 = xt * 64;

  const int lane = tid & 63, wv = tid >> 6;
  const int frow = lane & 15, kg = lane >> 4;

  __shared__ __align__(16) char BsRaw[64 * SG];   // 66560 B
  __shared__ __align__(16) char ZsRaw[64 * SG];   // z tile [dgrp][col][8] bf16

  // ---------------- encoder -> registers (h and xe never hit memory) ----
  f32x4 hreg[2][4], xer[2][4];
  {
    const float* xn = p.x + (size_t)n * T_;
#pragma unroll
    for (int jb = 0; jb < 4; ++jb) {
      int gl = l0 + jb * 16 + frow;
      int t0 = gl * 10 - 20;
      float xw[FK_];
#pragma unroll
      for (int k = 0; k < FK_; ++k) {
        int t = t0 + k;
        xw[k] = (t >= 0 && t < T_) ? xn[t] : 0.f;
      }
#pragma unroll
      for (int ia = 0; ia < 2; ++ia) {
#pragma unroll
        for (int jj = 0; jj < 4; ++jj) {
          int c = wv * 32 + ia * 16 + kg * 4 + jj;
          const float* w = p.w_enc + c * FK_;
          float acc = 0.f;
#pragma unroll
          for (int k = 0; k < FK_; ++k) acc = fmaf(xw[k], w[k], acc);
          hreg[ia][jb][jj] = acc;
          xer[ia][jb][jj] = acc;
        }
      }
    }
  }

  // ---------------- 32 residual blocks, fully fused ----------------
  for (int layer = 0; layer < NB_; ++layer) {
    const int dil = 1 << (layer & 7);
    const float* s1p = p.s1 + layer * C_;
    const float* o1p = p.o1 + layer * C_;
    const float* s2p = p.s2 + layer * D_;
    const float* o2p = p.o2 + layer * D_;
    const float* s3p = p.s3 + layer * D_;
    const float* o3p = p.o3 + layer * D_;

    // ===== B1 = BN1(hreg) -> Bs =====
#pragma unroll
    for (int ia = 0; ia < 2; ++ia) {
      int cb = wv * 32 + ia * 16 + kg * 4;
      float4 s1v = *(const float4*)(s1p + cb);
      float4 o1v = *(const float4*)(o1p + cb);
#pragma unroll
      for (int jb = 0; jb < 4; ++jb) {
        shortx4 pk;
        pk[0] = f2bf(fmaf(hreg[ia][jb][0], s1v.x, o1v.x));
        pk[1] = f2bf(fmaf(hreg[ia][jb][1], s1v.y, o1v.y));
        pk[2] = f2bf(fmaf(hreg[ia][jb][2], s1v.z, o1v.z));
        pk[3] = f2bf(fmaf(hreg[ia][jb][3], s1v.w, o1v.w));
        *(shortx4*)(BsRaw + (cb >> 3) * SG + (jb * 16 + frow) * 16 + (kg & 1) * 8) = pk;
      }
    }

    // ===== software prefetch: next layer's weights+params -> L2 =====
    // one touch per 128B line; consumed (waited) at end of this layer.
    int pfa = 0;
    float pfb = 0.f;
    if (layer + 1 < NB_) {
      const short* nx1 = p.w1b + (size_t)(layer + 1) * D_ * C_;
      const short* nx2 = p.w2b + (size_t)(layer + 1) * D_ * C_;
#pragma unroll
      for (int q = 0; q < 4; ++q) {
        pfa += (int)nx1[(tid * 4 + q) * 64];   // 2048 lines of W1
        pfa += (int)nx2[(tid * 4 + q) * 64];   // 2048 lines of W2
      }
      if (tid < 8)        pfb = p.s1[(layer + 1) * C_ + tid * 32];
      else if (tid < 16)  pfb = p.o1[(layer + 1) * C_ + (tid - 8) * 32];
      else if (tid < 32)  pfb = p.s2[(layer + 1) * D_ + (tid - 16) * 32];
      else if (tid < 48)  pfb = p.o2[(layer + 1) * D_ + (tid - 32) * 32];
      else if (tid < 64)  pfb = p.s3[(layer + 1) * D_ + (tid - 48) * 32];
      else if (tid < 80)  pfb = p.o3[(layer + 1) * D_ + (tid - 64) * 32];
      else if (tid < 128) pfb = p.wd[(size_t)(layer + 1) * D_ * 3 + (tid - 80) * 32];
    }
    __syncthreads();

    // ===== stage1 MFMA: acc1[d 512][l 64] ; wave owns 64 d rows =====
    f32x4 acc1[4][4] = {};
    {
      const short* W1 = p.w1b + (size_t)layer * D_ * C_;
#pragma unroll
      for (int k0 = 0; k0 < 8; ++k0) {
        int kb = k0 * 32 + kg * 8;
        bf16x8 bfr[4];
#pragma unroll
        for (int jb = 0; jb < 4; ++jb)
          bfr[jb] = *(bf16x8*)(BsRaw + (k0 * 4 + kg) * SG + (jb * 16 + frow) * 16);
#pragma unroll
        for (int ia = 0; ia < 4; ++ia) {
          bf16x8 af = *(const bf16x8*)(W1 + (size_t)(wv * 64 + ia * 16 + frow) * C_ + kb);
#pragma unroll
          for (int jb = 0; jb < 4; ++jb)
            acc1[ia][jb] = __builtin_amdgcn_mfma_f32_16x16x32_bf16(af, bfr[jb], acc1[ia][jb], 0, 0, 0);
        }
      }
    }

    // ===== z = BN2(acc1) -> zLds + sc1 publish (HALO COLUMNS ONLY) =====
    {
      const int w = (dil < 64) ? dil : 64;   // halo width each side
      unsigned short* zgl = p.zg + ((size_t)(layer * NBLK + bid)) * (64 * 512);
#pragma unroll
      for (int ia = 0; ia < 4; ++ia) {
        int db = wv * 64 + ia * 16 + kg * 4;
        float4 s2v = *(const float4*)(s2p + db);
        float4 o2v = *(const float4*)(o2p + db);
#pragma unroll
        for (int jb = 0; jb < 4; ++jb) {
          int l = jb * 16 + frow;
          shortx4 pk;
          pk[0] = f2bf(fmaf(acc1[ia][jb][0], s2v.x, o2v.x));
          pk[1] = f2bf(fmaf(acc1[ia][jb][1], s2v.y, o2v.y));
          pk[2] = f2bf(fmaf(acc1[ia][jb][2], s2v.z, o2v.z));
          pk[3] = f2bf(fmaf(acc1[ia][jb][3], s2v.w, o2v.w));
          *(shortx4*)(ZsRaw + (db >> 3) * SG + l * 16 + (kg & 1) * 8) = pk;
          if (l < w || l >= 64 - w) {
            unsigned long long u;
            __builtin_memcpy(&u, &pk, 8);
            __hip_atomic_store((unsigned long long*)(zgl + (size_t)l * 512 + db), u,
                               __ATOMIC_RELAXED, __HIP_MEMORY_SCOPE_AGENT);
          }
        }
      }
    }
    __syncthreads();   // zLds complete; sc1 publishes drained (vmcnt at s_barrier)
    if (tid == 0)
      __hip_atomic_store(&p.ct[bid], (unsigned)(layer + 1),
                         __ATOMIC_RELAXED, __HIP_MEMORY_SCOPE_AGENT);

    // ===== B3 = BN3(dconv(z)) two-pass: interior first, edges after spin =====
    {
      const float* wdp = p.wd + (size_t)layer * D_ * 3 + lane * 24;
      float4 wq[6];
#pragma unroll
      for (int q = 0; q < 6; ++q) wq[q] = *(const float4*)(wdp + 4 * q);
      float4 s3a = *(const float4*)(s3p + lane * 8), s3b = *(const float4*)(s3p + lane * 8 + 4);
      float4 o3a = *(const float4*)(o3p + lane * 8), o3b = *(const float4*)(o3p + lane * 8 + 4);
      const unsigned short* zlay = p.zg + (size_t)layer * NBLK * (64 * 512);

#pragma unroll
      for (int pass = 0; pass < 2; ++pass) {
        if (pass == 1) {
          // spin for neighbors' z (only the strips we actually read)
          if (tid == 0) {
            int step = (dil <= 64) ? 1 : 2;
            for (int s = -1; s <= 1; s += 2) {
              int xx = xt + s * step;
              if (xx < 0 || xx > 12) continue;
              const unsigned* c2 = &p.ct[n * 13 + xx];
              while (__hip_atomic_load((unsigned*)c2, __ATOMIC_RELAXED, __HIP_MEMORY_SCOPE_AGENT)
                     <= (unsigned)layer)
                __builtin_amdgcn_s_sleep(1);
            }
          }
          __syncthreads();
        }
#pragma unroll
        for (int r = 0; r < 8; ++r) {
          int row = wv * 8 + r;
          int gcol = l0 + row;
          int gl = gcol - dil, gr = gcol + dil;
          bool remL = (gl >= 0) && (gl < l0);
          bool remR = (gr < L_) && (gr >= l0 + 64);
          bool isRem = remL || remR;
          if ((pass == 0) == isRem) continue;
          bf16x8 zc = *(bf16x8*)(ZsRaw + lane * SG + row * 16);
          bf16x8 zl = {0, 0, 0, 0, 0, 0, 0, 0};
          bf16x8 zr = {0, 0, 0, 0, 0, 0, 0, 0};
          if (gl >= 0) {
            if (!remL) zl = *(bf16x8*)(ZsRaw + lane * SG + (gl - l0) * 16);
            else zl = *(const bf16x8*)(zlay + ((size_t)(n * 13 + (gl >> 6))) * (64 * 512)
                                       + (size_t)(gl & 63) * 512 + lane * 8);
          }
          if (gr < L_) {
            if (!remR) zr = *(bf16x8*)(ZsRaw + lane * SG + (gr - l0) * 16);
            else zr = *(const bf16x8*)(zlay + ((size_t)(n * 13 + (gr >> 6))) * (64 * 512)
                                       + (size_t)(gr & 63) * 512 + lane * 8);
          }
          bf16x8 pb;
#pragma unroll
          for (int j = 0; j < 8; ++j) {
            float w0 = wq[(3 * j + 0) >> 2][(3 * j + 0) & 3];
            float w1v = wq[(3 * j + 1) >> 2][(3 * j + 1) & 3];
            float w2v = wq[(3 * j + 2) >> 2][(3 * j + 2) & 3];
            float m = bf2f(zc[j]) * w1v;
            m = fmaf(bf2f(zl[j]), w0, m);
            m = fmaf(bf2f(zr[j]), w2v, m);
            float s3v = (j < 4) ? s3a[j] : s3b[j - 4];
            float o3v = (j < 4) ? o3a[j] : o3b[j - 4];
            pb[j] = f2bf(fmaf(m, s3v, o3v));
          }
          *(bf16x8*)(BsRaw + lane * SG + row * 16) = pb;
        }
      }
    }
    __syncthreads();

    // ===== stage2 MFMA: acc2[c 256][l 64] ; hreg += =====
    {
      f32x4 acc2[2][4] = {};
      const short* W2 = p.w2b + (size_t)layer * C_ * D_;
#pragma unroll
      for (int k0 = 0; k0 < 16; ++k0) {
        int kb = k0 * 32 + kg * 8;
        bf16x8 bfr[4];
#pragma unroll
        for (int jb = 0; jb < 4; ++jb)
          bfr[jb] = *(bf16x8*)(BsRaw + (k0 * 4 + kg) * SG + (jb * 16 + frow) * 16);
#pragma unroll
        for (int ia = 0; ia < 2; ++ia) {
          bf16x8 af = *(const bf16x8*)(W2 + (size_t)(wv * 32 + ia * 16 + frow) * D_ + kb);
#pragma unroll
          for (int jb = 0; jb < 4; ++jb)
            acc2[ia][jb] = __builtin_amdgcn_mfma_f32_16x16x32_bf16(af, bfr[jb], acc2[ia][jb], 0, 0, 0);
        }
      }
#pragma unroll
      for (int ia = 0; ia < 2; ++ia)
#pragma unroll
        for (int jb = 0; jb < 4; ++jb)
#pragma unroll
          for (int jj = 0; jj < 4; ++jj)
            hreg[ia][jb][jj] += acc2[ia][jb][jj];
    }
    // consume prefetch results here (drain after all compute; keeps loads live)
    asm volatile("" :: "v"(pfa), "v"(pfb));
    __syncthreads();   // Bs reads done before next layer's B1 writes
  }

  // ---------------- mask: y = xe * sigmoid(h) -> yb [n][l][c] ----------------
  {
    float* yn = p.yb + (size_t)n * ((size_t)L_ * C_);
#pragma unroll
    for (int ia = 0; ia < 2; ++ia) {
      int cb = wv * 32 + ia * 16 + kg * 4;
#pragma unroll
      for (int jb = 0; jb < 4; ++jb) {
        int gl = l0 + jb * 16 + frow;
        if (gl < L_) {
          float v[4];
#pragma unroll
          for (int jj = 0; jj < 4; ++jj)
            v[jj] = xer[ia][jb][jj] / (1.f + expf(-hreg[ia][jb][jj]));
          unsigned long long u0, u1;
          __builtin_memcpy(&u0, &v[0], 8);
          __builtin_memcpy(&u1, &v[2], 8);
          unsigned long long* dst = (unsigned long long*)(yn + (size_t)gl * C_ + cb);
          __hip_atomic_store(dst + 0, u0, __ATOMIC_RELAXED, __HIP_MEMORY_SCOPE_AGENT);
          __hip_atomic_store(dst + 1, u1, __ATOMIC_RELAXED, __HIP_MEMORY_SCOPE_AGENT);
        }
      }
    }
  }
  bar_heavy(p.gbar, NBLK, tid);

  // ---------------- decoder ----------------
  for (int idx = gtid; idx < NBATCH * T_; idx += NTH_G) {
    int t = idx % T_;
    int nn = idx / T_;
    int tt = t + FK_;
    int lq = tt / 10;      // in [2, 801]
    int k0 = tt % 10;
    const float* y0 = p.yb + (size_t)nn * ((size_t)L_ * C_) + (size_t)lq * C_;
    const float* y1 = y0 - C_;
    float acc = 0.f;
#pragma unroll 8
    for (int c = 0; c < C_; c++) {
      const float* wr2 = p.w_dec + c * FK_;
      acc = fmaf(y0[c], wr2[k0], acc);
      acc = fmaf(y1[c], wr2[k0 + 10], acc);
    }
    p.out[idx] = acc;
  }
}

extern "C" void kernel_launch(void* const* d_in, const int* in_sizes, int n_in,
                              void* d_out, int out_size, void* d_ws, size_t ws_size,
                              hipStream_t stream) {
  KParams hp;
  hp.x     = (const float*)d_in[0];
  hp.w_enc = (const float*)d_in[1];
  hp.w1    = (const float*)d_in[2];
  hp.wd    = (const float*)d_in[3];
  hp.w2    = (const float*)d_in[4];
  hp.w_dec = (const float*)d_in[5];
  hp.g1 = (const float*)d_in[6];  hp.bb1 = (const float*)d_in[7];
  hp.m1 = (const float*)d_in[8];  hp.v1  = (const float*)d_in[9];
  hp.g2 = (const float*)d_in[10]; hp.bb2 = (const float*)d_in[11];
  hp.m2 = (const float*)d_in[12]; hp.v2  = (const float*)d_in[13];
  hp.g3 = (const float*)d_in[14]; hp.bb3 = (const float*)d_in[15];
  hp.m3 = (const float*)d_in[16]; hp.v3  = (const float*)d_in[17];
  hp.out = (float*)d_out;

  char* cur = (char*)d_ws;
  auto take = [&](size_t bytes) { char* r = cur; cur += (bytes + 255) & ~(size_t)255; return r; };
  hp.gbar = (Bar*)take(256);
  hp.ct   = (unsigned*)take(NBLK * 4);
  hp.s1 = (float*)take(NB_ * C_ * 4);
  hp.o1 = (float*)take(NB_ * C_ * 4);
  hp.s2 = (float*)take(NB_ * D_ * 4);
  hp.o2 = (float*)take(NB_ * D_ * 4);
  hp.s3 = (float*)take(NB_ * D_ * 4);
  hp.o3 = (float*)take(NB_ * D_ * 4);
  hp.yb  = (float*)take((size_t)NBATCH * L_ * C_ * 4);
  hp.w1b = (short*)take((size_t)NB_ * D_ * C_ * 2);
  hp.w2b = (short*)take((size_t)NB_ * D_ * C_ * 2);
  hp.zg  = (unsigned short*)take((size_t)NB_ * NBLK * 64 * 512 * 2);   // 109 MB

  hipMemsetAsync(d_ws, 0, 1024, stream);   // gbar + ct
  prep_kernel<<<dim3(1024), dim3(256), 0, stream>>>(hp);
  tasnet_fused<<<dim3(NBLK), dim3(NTHR), 0, stream>>>(hp);
}

// Round 13
// 936.322 us; speedup vs baseline: 1.1006x; 1.1006x over previous
//
#include <hip/hip_runtime.h>
#include <cstddef>

#define T_     8000
#define L_     803
#define C_     256
#define D_     512
#define NB_    32
#define FK_    20
#define NBATCH 4
#define EPS_   1e-5f

#define NBLK   52            // 13 l-tiles x 4 batch; one block owns full C/D of a strip
#define NTHR   512           // 8 waves
#define NTH_G  (NBLK * NTHR)
#define SG     1040          // LDS k-group stride bytes: 64 cols * 16B + 16B pad

typedef __attribute__((ext_vector_type(8))) short bf16x8;
typedef __attribute__((ext_vector_type(4))) short shortx4;
typedef __attribute__((ext_vector_type(4))) float f32x4;

__device__ __forceinline__ short f2bf(float x) {
  unsigned u = __float_as_uint(x);
  u += 0x7FFF + ((u >> 16) & 1);   // RNE
  return (short)(u >> 16);
}
__device__ __forceinline__ float bf2f(short u) {
  return __uint_as_float(((unsigned)(unsigned short)u) << 16);
}

struct __align__(64) Bar { unsigned cnt; unsigned phase; unsigned pad[14]; };

__device__ __forceinline__ void bar_heavy(Bar* b, unsigned nblk, int tid) {
  __syncthreads();
  if (tid == 0) {
    __threadfence();
    unsigned ph = __hip_atomic_load(&b->phase, __ATOMIC_RELAXED, __HIP_MEMORY_SCOPE_AGENT);
    unsigned prev = __hip_atomic_fetch_add(&b->cnt, 1u, __ATOMIC_RELAXED, __HIP_MEMORY_SCOPE_AGENT);
    if (prev == nblk - 1) {
      __hip_atomic_store(&b->cnt, 0u, __ATOMIC_RELAXED, __HIP_MEMORY_SCOPE_AGENT);
      __hip_atomic_store(&b->phase, ph + 1u, __ATOMIC_RELEASE, __HIP_MEMORY_SCOPE_AGENT);
    } else {
      while (__hip_atomic_load(&b->phase, __ATOMIC_RELAXED, __HIP_MEMORY_SCOPE_AGENT) == ph)
        __builtin_amdgcn_s_sleep(2);
    }
    __threadfence();
  }
  __syncthreads();
}

struct KParams {
  const float *x, *w_enc, *w1, *wd, *w2, *w_dec;
  const float *g1, *bb1, *m1, *v1;
  const float *g2, *bb2, *m2, *v2;
  const float *g3, *bb3, *m3, *v3;
  float *out;
  float *s1, *o1, *s2, *o2, *s3, *o3;
  float *yb;                  // y [n][l][c] f32
  short *w1b, *w2b;           // bf16 weights
  unsigned short *zg;         // z publish: [layer][logical blk][64][512] bf16
  unsigned *ct;               // per-block monotone layer counter [52] (logical idx)
  Bar *gbar;
};

// ---------- full-grid prep: BN fold + weight bf16 conversion ----------
__global__ __launch_bounds__(256) void prep_kernel(KParams p) {
  const int gtid = blockIdx.x * 256 + threadIdx.x;
  const int stride = gridDim.x * 256;
  for (int i = gtid; i < NB_ * C_; i += stride) {
    float s = p.g1[i] * rsqrtf(p.v1[i] + EPS_);
    p.s1[i] = s; p.o1[i] = p.bb1[i] - p.m1[i] * s;
  }
  for (int i = gtid; i < NB_ * D_; i += stride) {
    float s2 = p.g2[i] * rsqrtf(p.v2[i] + EPS_);
    p.s2[i] = s2; p.o2[i] = p.bb2[i] - p.m2[i] * s2;
    float s3 = p.g3[i] * rsqrtf(p.v3[i] + EPS_);
    p.s3[i] = s3; p.o3[i] = p.bb3[i] - p.m3[i] * s3;
  }
  for (int i = gtid; i < NB_ * D_ * C_ / 4; i += stride) {
    float4 a = ((const float4*)p.w1)[i];
    float4 b = ((const float4*)p.w2)[i];
    shortx4 sa, sb;
    sa[0] = f2bf(a.x); sa[1] = f2bf(a.y); sa[2] = f2bf(a.z); sa[3] = f2bf(a.w);
    sb[0] = f2bf(b.x); sb[1] = f2bf(b.y); sb[2] = f2bf(b.z); sb[3] = f2bf(b.w);
    *(shortx4*)&p.w1b[4 * i] = sa;
    *(shortx4*)&p.w2b[4 * i] = sb;
  }
}

__global__ __launch_bounds__(NTHR, 2) void tasnet_fused(KParams p) {
  const int tid = threadIdx.x;
  const int bid = blockIdx.x;
  const int gtid = bid * NTHR + tid;

  // XCD-aware strip placement: bid%8 -> XCD (round-robin dispatch heuristic).
  // Batch n lives on XCD pair {n, n+4}: strips 0-6 on XCD n, strips 7-12 on n+4.
  // => 11 of 12 neighbor boundaries are same-XCD (halo exchange stays in L2).
  const int xcd = bid & 7, slot = bid >> 3;
  const int n = xcd & 3;
  const int xt = (xcd < 4) ? slot : 7 + slot;
  const int lg = n * 13 + xt;           // logical block id (zg/ct indexing)
  const int l0 = xt * 64;

  const int lane = tid & 63, wv = tid >> 6;
  const int frow = lane & 15, kg = lane >> 4;

  __shared__ __align__(16) char BsRaw[64 * SG];   // 66560 B
  __shared__ __align__(16) char ZsRaw[64 * SG];   // z tile [dgrp][col][8] bf16

  // ---------------- encoder -> registers (h and xe never hit memory) ----
  f32x4 hreg[2][4], xer[2][4];
  {
    const float* xn = p.x + (size_t)n * T_;
#pragma unroll
    for (int jb = 0; jb < 4; ++jb) {
      int gl = l0 + jb * 16 + frow;
      int t0 = gl * 10 - 20;
      float xw[FK_];
#pragma unroll
      for (int k = 0; k < FK_; ++k) {
        int t = t0 + k;
        xw[k] = (t >= 0 && t < T_) ? xn[t] : 0.f;
      }
#pragma unroll
      for (int ia = 0; ia < 2; ++ia) {
#pragma unroll
        for (int jj = 0; jj < 4; ++jj) {
          int c = wv * 32 + ia * 16 + kg * 4 + jj;
          const float* w = p.w_enc + c * FK_;
          float acc = 0.f;
#pragma unroll
          for (int k = 0; k < FK_; ++k) acc = fmaf(xw[k], w[k], acc);
          hreg[ia][jb][jj] = acc;
          xer[ia][jb][jj] = acc;
        }
      }
    }
  }

  // ---------------- 32 residual blocks, fully fused ----------------
  for (int layer = 0; layer < NB_; ++layer) {
    const int dil = 1 << (layer & 7);
    const float* s1p = p.s1 + layer * C_;
    const float* o1p = p.o1 + layer * C_;
    const float* s2p = p.s2 + layer * D_;
    const float* o2p = p.o2 + layer * D_;
    const float* s3p = p.s3 + layer * D_;
    const float* o3p = p.o3 + layer * D_;

    // ===== B1 = BN1(hreg) -> Bs =====
#pragma unroll
    for (int ia = 0; ia < 2; ++ia) {
      int cb = wv * 32 + ia * 16 + kg * 4;
      float4 s1v = *(const float4*)(s1p + cb);
      float4 o1v = *(const float4*)(o1p + cb);
#pragma unroll
      for (int jb = 0; jb < 4; ++jb) {
        shortx4 pk;
        pk[0] = f2bf(fmaf(hreg[ia][jb][0], s1v.x, o1v.x));
        pk[1] = f2bf(fmaf(hreg[ia][jb][1], s1v.y, o1v.y));
        pk[2] = f2bf(fmaf(hreg[ia][jb][2], s1v.z, o1v.z));
        pk[3] = f2bf(fmaf(hreg[ia][jb][3], s1v.w, o1v.w));
        *(shortx4*)(BsRaw + (cb >> 3) * SG + (jb * 16 + frow) * 16 + (kg & 1) * 8) = pk;
      }
    }
    __syncthreads();

    // ===== stage1 MFMA: acc1[d 512][l 64] ; wave owns 64 d rows =====
    f32x4 acc1[4][4] = {};
    {
      const short* W1 = p.w1b + (size_t)layer * D_ * C_;
#pragma unroll
      for (int k0 = 0; k0 < 8; ++k0) {
        int kb = k0 * 32 + kg * 8;
        bf16x8 bfr[4];
#pragma unroll
        for (int jb = 0; jb < 4; ++jb)
          bfr[jb] = *(bf16x8*)(BsRaw + (k0 * 4 + kg) * SG + (jb * 16 + frow) * 16);
#pragma unroll
        for (int ia = 0; ia < 4; ++ia) {
          bf16x8 af = *(const bf16x8*)(W1 + (size_t)(wv * 64 + ia * 16 + frow) * C_ + kb);
#pragma unroll
          for (int jb = 0; jb < 4; ++jb)
            acc1[ia][jb] = __builtin_amdgcn_mfma_f32_16x16x32_bf16(af, bfr[jb], acc1[ia][jb], 0, 0, 0);
        }
      }
    }

    // ===== z = BN2(acc1) -> zLds + halo publish (L2 for same-XCD reader) =====
    {
      const int step = (dil <= 64) ? 1 : 2;
      const int w = (dil < 64) ? dil : 64;
      const int rdL = xt - step, rdR = xt + step;   // readers of our edges
      const bool pubL = (rdL >= 0);
      const bool pubR = (rdR <= 12);
      const bool scL = pubL && ((rdL >= 7) != (xt >= 7));  // cross-XCD
      const bool scR = pubR && ((rdR >= 7) != (xt >= 7));
      unsigned short* zgl = p.zg + ((size_t)(layer * NBLK + lg)) * (64 * 512);
#pragma unroll
      for (int ia = 0; ia < 4; ++ia) {
        int db = wv * 64 + ia * 16 + kg * 4;
        float4 s2v = *(const float4*)(s2p + db);
        float4 o2v = *(const float4*)(o2p + db);
#pragma unroll
        for (int jb = 0; jb < 4; ++jb) {
          int l = jb * 16 + frow;
          shortx4 pk;
          pk[0] = f2bf(fmaf(acc1[ia][jb][0], s2v.x, o2v.x));
          pk[1] = f2bf(fmaf(acc1[ia][jb][1], s2v.y, o2v.y));
          pk[2] = f2bf(fmaf(acc1[ia][jb][2], s2v.z, o2v.z));
          pk[3] = f2bf(fmaf(acc1[ia][jb][3], s2v.w, o2v.w));
          *(shortx4*)(ZsRaw + (db >> 3) * SG + l * 16 + (kg & 1) * 8) = pk;
          bool needL = pubL && (l < w);
          bool needR = pubR && (l >= 64 - w);
          if (needL || needR) {
            unsigned long long u;
            __builtin_memcpy(&u, &pk, 8);
            unsigned long long* dst = (unsigned long long*)(zgl + (size_t)l * 512 + db);
            if ((needL && scL) || (needR && scR))
              __hip_atomic_store(dst, u, __ATOMIC_RELAXED, __HIP_MEMORY_SCOPE_AGENT);
            else
              *dst = u;    // same-XCD reader: dirty line in shared L2 is visible
          }
        }
      }
    }
    __syncthreads();   // zLds complete; publish stores drained (vmcnt at s_barrier)
    if (tid == 0)
      __hip_atomic_store(&p.ct[lg], (unsigned)(layer + 1),
                         __ATOMIC_RELAXED, __HIP_MEMORY_SCOPE_AGENT);

    // ===== B3 = BN3(dconv(z)) two-pass: interior first, edges after spin =====
    {
      const float* wdp = p.wd + (size_t)layer * D_ * 3 + lane * 24;
      float4 wq[6];
#pragma unroll
      for (int q = 0; q < 6; ++q) wq[q] = *(const float4*)(wdp + 4 * q);
      float4 s3a = *(const float4*)(s3p + lane * 8), s3b = *(const float4*)(s3p + lane * 8 + 4);
      float4 o3a = *(const float4*)(o3p + lane * 8), o3b = *(const float4*)(o3p + lane * 8 + 4);
      const unsigned short* zlay = p.zg + (size_t)layer * NBLK * (64 * 512);

#pragma unroll
      for (int pass = 0; pass < 2; ++pass) {
        if (pass == 1) {
          // spin for neighbors' z (only the strips we actually read)
          if (tid == 0) {
            int step = (dil <= 64) ? 1 : 2;
            for (int s = -1; s <= 1; s += 2) {
              int xx = xt + s * step;
              if (xx < 0 || xx > 12) continue;
              const unsigned* c2 = &p.ct[n * 13 + xx];
              while (__hip_atomic_load((unsigned*)c2, __ATOMIC_RELAXED, __HIP_MEMORY_SCOPE_AGENT)
                     <= (unsigned)layer)
                __builtin_amdgcn_s_sleep(1);
            }
          }
          __syncthreads();
        }
#pragma unroll
        for (int r = 0; r < 8; ++r) {
          int row = wv * 8 + r;
          int gcol = l0 + row;
          int gl = gcol - dil, gr = gcol + dil;
          bool remL = (gl >= 0) && (gl < l0);
          bool remR = (gr < L_) && (gr >= l0 + 64);
          bool isRem = remL || remR;
          if ((pass == 0) == isRem) continue;
          bf16x8 zc = *(bf16x8*)(ZsRaw + lane * SG + row * 16);
          bf16x8 zl = {0, 0, 0, 0, 0, 0, 0, 0};
          bf16x8 zr = {0, 0, 0, 0, 0, 0, 0, 0};
          if (gl >= 0) {
            if (!remL) zl = *(bf16x8*)(ZsRaw + lane * SG + (gl - l0) * 16);
            else zl = *(const bf16x8*)(zlay + ((size_t)(n * 13 + (gl >> 6))) * (64 * 512)
                                       + (size_t)(gl & 63) * 512 + lane * 8);
          }
          if (gr < L_) {
            if (!remR) zr = *(bf16x8*)(ZsRaw + lane * SG + (gr - l0) * 16);
            else zr = *(const bf16x8*)(zlay + ((size_t)(n * 13 + (gr >> 6))) * (64 * 512)
                                       + (size_t)(gr & 63) * 512 + lane * 8);
          }
          bf16x8 pb;
#pragma unroll
          for (int j = 0; j < 8; ++j) {
            float w0 = wq[(3 * j + 0) >> 2][(3 * j + 0) & 3];
            float w1v = wq[(3 * j + 1) >> 2][(3 * j + 1) & 3];
            float w2v = wq[(3 * j + 2) >> 2][(3 * j + 2) & 3];
            float m = bf2f(zc[j]) * w1v;
            m = fmaf(bf2f(zl[j]), w0, m);
            m = fmaf(bf2f(zr[j]), w2v, m);
            float s3v = (j < 4) ? s3a[j] : s3b[j - 4];
            float o3v = (j < 4) ? o3a[j] : o3b[j - 4];
            pb[j] = f2bf(fmaf(m, s3v, o3v));
          }
          *(bf16x8*)(BsRaw + lane * SG + row * 16) = pb;
        }
      }
    }
    __syncthreads();

    // ===== stage2 MFMA: acc2[c 256][l 64] ; hreg += =====
    {
      f32x4 acc2[2][4] = {};
      const short* W2 = p.w2b + (size_t)layer * C_ * D_;
#pragma unroll
      for (int k0 = 0; k0 < 16; ++k0) {
        int kb = k0 * 32 + kg * 8;
        bf16x8 bfr[4];
#pragma unroll
        for (int jb = 0; jb < 4; ++jb)
          bfr[jb] = *(bf16x8*)(BsRaw + (k0 * 4 + kg) * SG + (jb * 16 + frow) * 16);
#pragma unroll
        for (int ia = 0; ia < 2; ++ia) {
          bf16x8 af = *(const bf16x8*)(W2 + (size_t)(wv * 32 + ia * 16 + frow) * D_ + kb);
#pragma unroll
          for (int jb = 0; jb < 4; ++jb)
            acc2[ia][jb] = __builtin_amdgcn_mfma_f32_16x16x32_bf16(af, bfr[jb], acc2[ia][jb], 0, 0, 0);
        }
      }
#pragma unroll
      for (int ia = 0; ia < 2; ++ia)
#pragma unroll
        for (int jb = 0; jb < 4; ++jb)
#pragma unroll
          for (int jj = 0; jj < 4; ++jj)
            hreg[ia][jb][jj] += acc2[ia][jb][jj];
    }
    __syncthreads();   // Bs reads done before next layer's B1 writes
  }

  // ---------------- mask: y = xe * sigmoid(h) -> yb [n][l][c] ----------------
  {
    float* yn = p.yb + (size_t)n * ((size_t)L_ * C_);
#pragma unroll
    for (int ia = 0; ia < 2; ++ia) {
      int cb = wv * 32 + ia * 16 + kg * 4;
#pragma unroll
      for (int jb = 0; jb < 4; ++jb) {
        int gl = l0 + jb * 16 + frow;
        if (gl < L_) {
          float v[4];
#pragma unroll
          for (int jj = 0; jj < 4; ++jj)
            v[jj] = xer[ia][jb][jj] / (1.f + expf(-hreg[ia][jb][jj]));
          unsigned long long u0, u1;
          __builtin_memcpy(&u0, &v[0], 8);
          __builtin_memcpy(&u1, &v[2], 8);
          unsigned long long* dst = (unsigned long long*)(yn + (size_t)gl * C_ + cb);
          __hip_atomic_store(dst + 0, u0, __ATOMIC_RELAXED, __HIP_MEMORY_SCOPE_AGENT);
          __hip_atomic_store(dst + 1, u1, __ATOMIC_RELAXED, __HIP_MEMORY_SCOPE_AGENT);
        }
      }
    }
  }
  bar_heavy(p.gbar, NBLK, tid);

  // ---------------- decoder ----------------
  for (int idx = gtid; idx < NBATCH * T_; idx += NTH_G) {
    int t = idx % T_;
    int nn = idx / T_;
    int tt = t + FK_;
    int lq = tt / 10;      // in [2, 801]
    int k0 = tt % 10;
    const float* y0 = p.yb + (size_t)nn * ((size_t)L_ * C_) + (size_t)lq * C_;
    const float* y1 = y0 - C_;
    float acc = 0.f;
#pragma unroll 8
    for (int c = 0; c < C_; c++) {
      const float* wr2 = p.w_dec + c * FK_;
      acc = fmaf(y0[c], wr2[k0], acc);
      acc = fmaf(y1[c], wr2[k0 + 10], acc);
    }
    p.out[idx] = acc;
  }
}

extern "C" void kernel_launch(void* const* d_in, const int* in_sizes, int n_in,
                              void* d_out, int out_size, void* d_ws, size_t ws_size,
                              hipStream_t stream) {
  KParams hp;
  hp.x     = (const float*)d_in[0];
  hp.w_enc = (const float*)d_in[1];
  hp.w1    = (const float*)d_in[2];
  hp.wd    = (const float*)d_in[3];
  hp.w2    = (const float*)d_in[4];
  hp.w_dec = (const float*)d_in[5];
  hp.g1 = (const float*)d_in[6];  hp.bb1 = (const float*)d_in[7];
  hp.m1 = (const float*)d_in[8];  hp.v1  = (const float*)d_in[9];
  hp.g2 = (const float*)d_in[10]; hp.bb2 = (const float*)d_in[11];
  hp.m2 = (const float*)d_in[12]; hp.v2  = (const float*)d_in[13];
  hp.g3 = (const float*)d_in[14]; hp.bb3 = (const float*)d_in[15];
  hp.m3 = (const float*)d_in[16]; hp.v3  = (const float*)d_in[17];
  hp.out = (float*)d_out;

  char* cur = (char*)d_ws;
  auto take = [&](size_t bytes) { char* r = cur; cur += (bytes + 255) & ~(size_t)255; return r; };
  hp.gbar = (Bar*)take(256);
  hp.ct   = (unsigned*)take(NBLK * 4);
  hp.s1 = (float*)take(NB_ * C_ * 4);
  hp.o1 = (float*)take(NB_ * C_ * 4);
  hp.s2 = (float*)take(NB_ * D_ * 4);
  hp.o2 = (float*)take(NB_ * D_ * 4);
  hp.s3 = (float*)take(NB_ * D_ * 4);
  hp.o3 = (float*)take(NB_ * D_ * 4);
  hp.yb  = (float*)take((size_t)NBATCH * L_ * C_ * 4);
  hp.w1b = (short*)take((size_t)NB_ * D_ * C_ * 2);
  hp.w2b = (short*)take((size_t)NB_ * D_ * C_ * 2);
  hp.zg  = (unsigned short*)take((size_t)NB_ * NBLK * 64 * 512 * 2);   // 109 MB

  hipMemsetAsync(d_ws, 0, 1024, stream);   // gbar + ct
  prep_kernel<<<dim3(1024), dim3(256), 0, stream>>>(hp);
  tasnet_fused<<<dim3(NBLK), dim3(NTHR), 0, stream>>>(hp);
}